// Round 1
// baseline (849.299 us; speedup 1.0000x reference)
//
#include <hip/hip_runtime.h>

// NetVLAD fused kernel — fp32 baseline (round 1: correctness-first).
// B=32, N=4096, D=256, K=128, Dc=64.
// Phase 1: per 32-row tile: logits=X@Wa^T+ba -> softmax, h=leaky(X@W1^T+b1),
//          sq=h@W2^T+b2, accumulate agg[k][d] += assign[r][k]*sq[r][d] and
//          mass[k] += assign[r][k] into per-thread registers, atomics at end.
// Phase 2: vlad = agg - mass*centroid, L2-normalize per batch.

#define B_   32
#define N_   4096
#define D_   256
#define K_   128
#define DC_  64
#define TN   32      // rows per tile
#define CH   32      // d-chunk
#define NCHUNK 8     // D_/CH
#define TILES  8     // tiles per block
#define BLKPB  16    // blocks per batch  (BLKPB*TILES*TN == N_)
#define NEG  0.01f

struct ChunkPhase {
  float Xc[TN][36];      // desc tile chunk (pad 36)
  float WaC[CH][132];    // Wa chunk transposed: WaC[dd][k]
  float W1C[CH][68];     // W1 chunk transposed: W1C[dd][e]
};
struct PostPhase {
  float As[TN][132];     // logits -> assign
  float Hs[TN][68];      // h after leaky
  float W2T[DC_][68];    // W2 transposed: W2T[e][f]
  float Sq[TN][68];      // sq
  float pm[TN][8];
  float ps[TN][8];
};
union SmemU { ChunkPhase c; PostPhase p; };   // 53760 B

__device__ __forceinline__ float f4get(const float4& v, int j) {
  return j == 0 ? v.x : j == 1 ? v.y : j == 2 ? v.z : v.w;
}
__device__ __forceinline__ void fma4(float4& a, const float4& w, float x) {
  a.x = fmaf(w.x, x, a.x); a.y = fmaf(w.y, x, a.y);
  a.z = fmaf(w.z, x, a.z); a.w = fmaf(w.w, x, a.w);
}
__device__ __forceinline__ float4 add4(const float4& a, const float4& b) {
  return make_float4(a.x + b.x, a.y + b.y, a.z + b.z, a.w + b.w);
}

__global__ __launch_bounds__(256, 2)
void netvlad_phase1(const float* __restrict__ desc, const float* __restrict__ W1,
                    const float* __restrict__ b1, const float* __restrict__ W2,
                    const float* __restrict__ b2, const float* __restrict__ Wa,
                    const float* __restrict__ ba, float* __restrict__ agg,
                    float* __restrict__ mass)
{
  __shared__ SmemU u;
  const int t   = threadIdx.x;
  const int b   = blockIdx.x >> 4;
  const int blk = blockIdx.x & 15;

  const int kq = t & 15;    // GEMM1: k-quads 4*kq and 64+4*kq ; GEMM2/3 col-quad
  const int rg = t >> 4;    // 0..15
  const int r0 = rg << 1;   // rows r0, r0+1
  const int dp = t & 31;    // StepD: d pair base
  const int d0 = dp << 1;
  const int kg = t >> 5;    // StepD: k group
  const int kb = kg << 4;   // 16 k's
  const int sr = t >> 3;    // softmax row
  const int sp = t & 7;     // softmax part (16 k's each)

  float accA[16][2];
  #pragma unroll
  for (int i = 0; i < 16; ++i) { accA[i][0] = 0.f; accA[i][1] = 0.f; }
  float massAcc = 0.f;

  const float4 zero4 = make_float4(0.f, 0.f, 0.f, 0.f);

  for (int tile = 0; tile < TILES; ++tile) {
    const int n0 = (blk * TILES + tile) * TN;
    float4 accLa[2] = {zero4, zero4};
    float4 accLb[2] = {zero4, zero4};
    float4 accH[2]  = {zero4, zero4};

    for (int c = 0; c < NCHUNK; ++c) {
      const int dd0 = c * CH;
      // ---- stage Xc (256 float4), WaC, W1C ----
      {
        const int r  = t >> 3;
        const int dq = t & 7;
        float4 x = ((const float4*)desc)[(size_t)(b * N_ + n0 + r) * (D_/4) + (dd0 >> 2) + dq];
        *(float4*)&u.c.Xc[r][dq * 4] = x;
        #pragma unroll
        for (int it = 0; it < (K_ * CH) / 256; ++it) {
          int idx = t + it * 256;
          int k = idx >> 5, dd = idx & 31;
          u.c.WaC[dd][k] = Wa[k * D_ + dd0 + dd];
        }
        #pragma unroll
        for (int it = 0; it < (DC_ * CH) / 256; ++it) {
          int idx = t + it * 256;
          int e = idx >> 5, dd = idx & 31;
          u.c.W1C[dd][e] = W1[e * D_ + dd0 + dd];
        }
      }
      __syncthreads();
      // ---- GEMM1 (logits) + GEMM2 (h) accumulate ----
      #pragma unroll
      for (int d4 = 0; d4 < 8; ++d4) {
        float4 x0 = *(const float4*)&u.c.Xc[r0][d4 * 4];
        float4 x1 = *(const float4*)&u.c.Xc[r0 + 1][d4 * 4];
        #pragma unroll
        for (int j = 0; j < 4; ++j) {
          float xs0 = f4get(x0, j), xs1 = f4get(x1, j);
          float4 wa = *(const float4*)&u.c.WaC[d4 * 4 + j][kq * 4];
          float4 wb = *(const float4*)&u.c.WaC[d4 * 4 + j][64 + kq * 4];
          float4 w1 = *(const float4*)&u.c.W1C[d4 * 4 + j][kq * 4];
          fma4(accLa[0], wa, xs0); fma4(accLa[1], wa, xs1);
          fma4(accLb[0], wb, xs0); fma4(accLb[1], wb, xs1);
          fma4(accH[0],  w1, xs0); fma4(accH[1],  w1, xs1);
        }
      }
      __syncthreads();
    }

    // ---- write logits (+ba) and Hs (+b1, leaky); stage W2T ----
    {
      float4 baa = ((const float4*)ba)[kq];
      float4 bab = ((const float4*)ba)[16 + kq];
      float4 b1v = ((const float4*)b1)[kq];
      #pragma unroll
      for (int i = 0; i < 2; ++i) {
        *(float4*)&u.p.As[r0 + i][kq * 4]      = add4(accLa[i], baa);
        *(float4*)&u.p.As[r0 + i][64 + kq * 4] = add4(accLb[i], bab);
        float4 h = add4(accH[i], b1v);
        h.x = h.x >= 0.f ? h.x : NEG * h.x;
        h.y = h.y >= 0.f ? h.y : NEG * h.y;
        h.z = h.z >= 0.f ? h.z : NEG * h.z;
        h.w = h.w >= 0.f ? h.w : NEG * h.w;
        *(float4*)&u.p.Hs[r0 + i][kq * 4] = h;
      }
      #pragma unroll
      for (int it = 0; it < (DC_ * DC_) / 256; ++it) {
        int idx = t + it * 256;
        int f = idx >> 6, e = idx & 63;
        u.p.W2T[e][f] = W2[f * DC_ + e];
      }
    }
    __syncthreads();

    // ---- softmax over k per row ----
    {
      float m = -1e30f;
      #pragma unroll
      for (int i = 0; i < 16; ++i) m = fmaxf(m, u.p.As[sr][sp * 16 + i]);
      u.p.pm[sr][sp] = m;
    }
    __syncthreads();
    {
      float M = u.p.pm[sr][0];
      #pragma unroll
      for (int q = 1; q < 8; ++q) M = fmaxf(M, u.p.pm[sr][q]);
      float s = 0.f;
      #pragma unroll
      for (int i = 0; i < 16; ++i) {
        float e = __expf(u.p.As[sr][sp * 16 + i] - M);
        u.p.As[sr][sp * 16 + i] = e;
        s += e;
      }
      u.p.ps[sr][sp] = s;
    }
    __syncthreads();
    {
      float S = 0.f;
      #pragma unroll
      for (int q = 0; q < 8; ++q) S += u.p.ps[sr][q];
      float inv = 1.0f / S;
      #pragma unroll
      for (int i = 0; i < 16; ++i) u.p.As[sr][sp * 16 + i] *= inv;
    }

    // ---- GEMM3: sq = Hs @ W2^T + b2 ----
    {
      float4 accS[2] = {zero4, zero4};
      #pragma unroll
      for (int e4 = 0; e4 < 16; ++e4) {
        float4 h0 = *(const float4*)&u.p.Hs[r0][e4 * 4];
        float4 h1 = *(const float4*)&u.p.Hs[r0 + 1][e4 * 4];
        #pragma unroll
        for (int j = 0; j < 4; ++j) {
          float4 w = *(const float4*)&u.p.W2T[e4 * 4 + j][kq * 4];
          fma4(accS[0], w, f4get(h0, j));
          fma4(accS[1], w, f4get(h1, j));
        }
      }
      float4 b2v = ((const float4*)b2)[kq];
      *(float4*)&u.p.Sq[r0][kq * 4]     = add4(accS[0], b2v);
      *(float4*)&u.p.Sq[r0 + 1][kq * 4] = add4(accS[1], b2v);
    }
    __syncthreads();

    // ---- Step D: accA[kk][dd] += assign[r][kb+kk] * sq[r][d0+dd]; mass ----
    for (int r = 0; r < TN; ++r) {
      float2 s2 = *(const float2*)&u.p.Sq[r][d0];
      #pragma unroll
      for (int q = 0; q < 4; ++q) {
        float4 a = *(const float4*)&u.p.As[r][kb + 4 * q];
        accA[4*q+0][0] = fmaf(a.x, s2.x, accA[4*q+0][0]);
        accA[4*q+0][1] = fmaf(a.x, s2.y, accA[4*q+0][1]);
        accA[4*q+1][0] = fmaf(a.y, s2.x, accA[4*q+1][0]);
        accA[4*q+1][1] = fmaf(a.y, s2.y, accA[4*q+1][1]);
        accA[4*q+2][0] = fmaf(a.z, s2.x, accA[4*q+2][0]);
        accA[4*q+2][1] = fmaf(a.z, s2.y, accA[4*q+2][1]);
        accA[4*q+3][0] = fmaf(a.w, s2.x, accA[4*q+3][0]);
        accA[4*q+3][1] = fmaf(a.w, s2.y, accA[4*q+3][1]);
      }
    }
    if (t < K_) {
      for (int r = 0; r < TN; ++r) massAcc += u.p.As[r][t];
    }
    __syncthreads();  // before next tile overwrites As/Sq (union aliasing)
  }

  // ---- flush accumulators ----
  float* aggB = agg + (size_t)b * (K_ * DC_);
  #pragma unroll
  for (int kk = 0; kk < 16; ++kk) {
    atomicAdd(&aggB[(kb + kk) * DC_ + d0],     accA[kk][0]);
    atomicAdd(&aggB[(kb + kk) * DC_ + d0 + 1], accA[kk][1]);
  }
  if (t < K_) atomicAdd(&mass[b * K_ + t], massAcc);
}

__global__ __launch_bounds__(256)
void netvlad_phase2(const float* __restrict__ agg, const float* __restrict__ mass,
                    const float* __restrict__ centroid, float* __restrict__ out)
{
  __shared__ float v[K_ * DC_];
  __shared__ float red[4];
  const int b = blockIdx.x, t = threadIdx.x;
  float ss = 0.f;
  for (int idx = t; idx < K_ * DC_; idx += 256) {
    int k = idx >> 6;
    float val = agg[(size_t)b * K_ * DC_ + idx] - mass[b * K_ + k] * centroid[idx];
    v[idx] = val;
    ss += val * val;
  }
  #pragma unroll
  for (int off = 32; off > 0; off >>= 1) ss += __shfl_down(ss, off, 64);
  if ((t & 63) == 0) red[t >> 6] = ss;
  __syncthreads();
  if (t == 0) {
    float s = red[0] + red[1] + red[2] + red[3];
    red[0] = 1.0f / fmaxf(sqrtf(s), 1e-12f);
  }
  __syncthreads();
  float inv = red[0];
  for (int idx = t; idx < K_ * DC_; idx += 256)
    out[(size_t)b * K_ * DC_ + idx] = v[idx] * inv;
}

extern "C" void kernel_launch(void* const* d_in, const int* in_sizes, int n_in,
                              void* d_out, int out_size, void* d_ws, size_t ws_size,
                              hipStream_t stream) {
  const float* desc     = (const float*)d_in[0];
  const float* W1       = (const float*)d_in[1];
  const float* b1       = (const float*)d_in[2];
  const float* W2       = (const float*)d_in[3];
  const float* b2       = (const float*)d_in[4];
  const float* Wa       = (const float*)d_in[5];
  const float* ba       = (const float*)d_in[6];
  const float* centroid = (const float*)d_in[7];
  float* out = (float*)d_out;

  float* agg  = (float*)d_ws;                 // B*K*Dc
  float* mass = agg + B_ * K_ * DC_;          // B*K
  size_t zbytes = (size_t)(B_ * K_ * DC_ + B_ * K_) * sizeof(float);
  hipMemsetAsync(d_ws, 0, zbytes, stream);

  netvlad_phase1<<<dim3(B_ * BLKPB), dim3(256), 0, stream>>>(
      desc, W1, b1, W2, b2, Wa, ba, agg, mass);
  netvlad_phase2<<<dim3(B_), dim3(256), 0, stream>>>(agg, mass, centroid, out);
}

// Round 2
// 294.504 us; speedup vs baseline: 2.8838x; 2.8838x over previous
//
#include <hip/hip_runtime.h>

// NetVLAD — bf16 MFMA version (round 2).
// B=32, N=4096, D=256, K=128, Dc=64.
// Phase1: grid 256 (8 blocks/batch, 512 rows each), 256 thr (4 waves), 1 blk/CU.
//   Per 32-row iter: GEMM1/2 (logits+h) via 16x16x32 bf16 MFMA from frag-order
//   LDS; softmax in-register (shfl_xor over lane&15) + cross-wave LDS exchange;
//   GEMM3 (sq); aggregation agg=A^T*S via MFMA; agg acc in VGPRs, atomicAdd at end.
// Phase2: vlad = agg - mass*centroid, L2-normalize.
//
// MFMA 16x16x32 layouts (m89/m120-verified):
//   A: lane holds A[m=lane&15][k=(lane>>4)*8+j], 8 bf16
//   B: lane holds B[k=(lane>>4)*8+j][n=lane&15]
//   C/D: lane holds D[row=(lane>>4)*4+reg][col=lane&15], 4 f32

#define B_   32
#define N_   4096
#define D_   256
#define K_   128
#define DC_  64
#define ITERS 16          // 32-row iters per block (512 rows)
#define NEG  0.01f

typedef __attribute__((ext_vector_type(8))) short bf16x8;
typedef __attribute__((ext_vector_type(4))) float f32x4;

// LDS byte offsets (dynamic LDS, total 139776 B)
#define WA_OFF   0        // 8ct x 8ks x 64 lanes x 16B = 65536
#define W1_OFF   65536    // 4ct x 8ks -> 32768
#define W2_OFF   98304    // 4ct3 x 2ks3 -> 8192
#define XF_OFF   106496   // 2rt x 8ks -> 16384
#define AT_OFF   122880   // 8mt -> 8192
#define SF_OFF   131072   // 4nt -> 4096
#define HF_OFF   135168   // 2rt x 2ks3 -> 4096
#define SMAX_OFF 139264   // float[4][16]
#define SSUM_OFF 139520   // float[4][16]
#define LDS_BYTES 139776

__device__ __forceinline__ unsigned short f2bf(float x) {
  union { float f; unsigned u; } v; v.f = x;
  unsigned r = v.u + 0x7fffu + ((v.u >> 16) & 1u);
  return (unsigned short)(r >> 16);
}
__device__ __forceinline__ unsigned pack2(float a, float b) {
  return (unsigned)f2bf(a) | ((unsigned)f2bf(b) << 16);
}
__device__ __forceinline__ bf16x8 ldf(const char* s, int off) {
  return *reinterpret_cast<const bf16x8*>(s + off);
}

__global__ __launch_bounds__(256, 1)
void netvlad_phase1(const float* __restrict__ desc, const float* __restrict__ W1,
                    const float* __restrict__ b1, const float* __restrict__ W2,
                    const float* __restrict__ b2, const float* __restrict__ Wa,
                    const float* __restrict__ ba, float* __restrict__ agg,
                    float* __restrict__ mass)
{
  extern __shared__ char smem[];
  const int t    = threadIdx.x;
  const int b    = blockIdx.x >> 3;
  const int blk  = blockIdx.x & 7;
  const int w    = t >> 6;         // wave 0..3
  const int lane = t & 63;
  const int li   = lane & 15;
  const int quad = lane >> 4;
  const int rt   = w >> 1;         // row-tile 0/1 within 32-row iter
  const int half = w & 1;          // col half: 0 -> Wa ct 0..5 ; 1 -> Wa 6,7 + W1 0..3
  const int nWa  = half ? 2 : 6;

  // ---- one-time: stage all weights into frag-order LDS ----
  for (int p = t; p < 6656; p += 256) {
    const float* src; int dstoff;
    if (p < 4096) {            // WaF: ct(8) x ks(8) x L(64)
      int L = p & 63;
      int row = ((p >> 9) << 4) + (L & 15);
      int col = (((p >> 6) & 7) << 5) + ((L >> 4) << 3);
      src = Wa + row * D_ + col;  dstoff = WA_OFF + p * 16;
    } else if (p < 6144) {     // W1F: ct(4) x ks(8) x L(64)
      int q = p - 4096; int L = q & 63;
      int row = ((q >> 9) << 4) + (L & 15);
      int col = (((q >> 6) & 7) << 5) + ((L >> 4) << 3);
      src = W1 + row * D_ + col;  dstoff = W1_OFF + q * 16;
    } else {                   // W2F: ct3(4) x ks3(2) x L(64)
      int q = p - 6144; int L = q & 63;
      int row = ((q >> 7) << 4) + (L & 15);
      int col = (((q >> 6) & 1) << 5) + ((L >> 4) << 3);
      src = W2 + row * DC_ + col; dstoff = W2_OFF + q * 16;
    }
    float4 a = *(const float4*)src;
    float4 c = *(const float4*)(src + 4);
    uint4 o; o.x = pack2(a.x, a.y); o.y = pack2(a.z, a.w);
    o.z = pack2(c.x, c.y); o.w = pack2(c.z, c.w);
    *reinterpret_cast<uint4*>(smem + dstoff) = o;
  }

  // ---- biases (hoisted) ----
  float biasr[6];
  #pragma unroll
  for (int j = 0; j < 6; ++j) {
    int g = half * 6 + j;
    biasr[j] = (g < 8) ? ba[g * 16 + li] : b1[(g - 8) * 16 + li];
  }
  float b2r[2];
  #pragma unroll
  for (int c = 0; c < 2; ++c) b2r[c] = b2[(half * 2 + c) * 16 + li];

  // ---- X tile staging: prefetch regs + frag-order LDS write ----
  float4 xp[8];
  auto issueX = [&](int it_next) {
    const int n0n = blk * 512 + it_next * 32;
    #pragma unroll
    for (int i = 0; i < 4; ++i) {
      int p = t + i * 256;
      int L = p & 63;
      const float* src = desc + ((size_t)b * N_ + n0n + ((p >> 9) << 4) + (L & 15)) * D_
                       + (((p >> 6) & 7) << 5) + ((L >> 4) << 3);
      xp[2 * i]     = *(const float4*)src;
      xp[2 * i + 1] = *(const float4*)(src + 4);
    }
  };
  auto writeX = [&]() {
    #pragma unroll
    for (int i = 0; i < 4; ++i) {
      uint4 o;
      o.x = pack2(xp[2 * i].x,     xp[2 * i].y);
      o.y = pack2(xp[2 * i].z,     xp[2 * i].w);
      o.z = pack2(xp[2 * i + 1].x, xp[2 * i + 1].y);
      o.w = pack2(xp[2 * i + 1].z, xp[2 * i + 1].w);
      *reinterpret_cast<uint4*>(smem + XF_OFF + (t + i * 256) * 16) = o;
    }
  };

  issueX(0); writeX(); issueX(1);

  f32x4 gacc[2][4];
  #pragma unroll
  for (int m = 0; m < 2; ++m)
    #pragma unroll
    for (int nt = 0; nt < 4; ++nt) gacc[m][nt] = (f32x4){0.f, 0.f, 0.f, 0.f};
  float massA[6] = {0.f, 0.f, 0.f, 0.f, 0.f, 0.f};

  __syncthreads();   // weights + XF_0 ready

  for (int it = 0; it < ITERS; ++it) {
    // ---- GEMM1/2 k-loop: logits (Wa tiles) + h (W1 tiles) ----
    f32x4 accT[6];
    #pragma unroll
    for (int j = 0; j < 6; ++j) accT[j] = (f32x4){0.f, 0.f, 0.f, 0.f};
    #pragma unroll
    for (int ks = 0; ks < 8; ++ks) {
      bf16x8 xa = ldf(smem, XF_OFF + ((rt * 8 + ks) * 64 + lane) * 16);
      #pragma unroll
      for (int j = 0; j < 6; ++j) {
        int g = half * 6 + j;
        int boff = (g < 8) ? (WA_OFF + (g * 8 + ks) * 1024)
                           : (W1_OFF + ((g - 8) * 8 + ks) * 1024);
        bf16x8 wb = ldf(smem, boff + lane * 16);
        accT[j] = __builtin_amdgcn_mfma_f32_16x16x32_bf16(xa, wb, accT[j], 0, 0, 0);
      }
    }
    #pragma unroll
    for (int j = 0; j < 6; ++j) {
      accT[j][0] += biasr[j]; accT[j][1] += biasr[j];
      accT[j][2] += biasr[j]; accT[j][3] += biasr[j];
    }

    // ---- softmax part 1: per-row max over this wave's Wa tiles ----
    float m4[4];
    #pragma unroll
    for (int r = 0; r < 4; ++r) {
      float m = -1e30f;
      for (int j = 0; j < nWa; ++j) m = fmaxf(m, accT[j][r]);
      #pragma unroll
      for (int off = 1; off < 16; off <<= 1) m = fmaxf(m, __shfl_xor(m, off, 64));
      m4[r] = m;
    }
    if (li == 0) {
      #pragma unroll
      for (int r = 0; r < 4; ++r)
        *reinterpret_cast<float*>(smem + SMAX_OFF + ((rt * 2 + half) * 16 + quad * 4 + r) * 4) = m4[r];
    }
    __syncthreads();  // (1) kloop done everywhere; XF dead; smax ready

    // stage next X tile (XF free now); prefetch the one after
    if (it + 1 < ITERS) {
      writeX();
      if (it + 2 < ITERS) issueX(it + 2);
    }

    // ---- softmax part 2: exp + per-row sum ----
    float s4[4], M4[4];
    #pragma unroll
    for (int r = 0; r < 4; ++r) {
      float other = *reinterpret_cast<float*>(smem + SMAX_OFF + ((rt * 2 + (1 - half)) * 16 + quad * 4 + r) * 4);
      M4[r] = fmaxf(m4[r], other);
      float s = 0.f;
      for (int j = 0; j < nWa; ++j) {
        float e = __expf(accT[j][r] - M4[r]);
        accT[j][r] = e;
        s += e;
      }
      #pragma unroll
      for (int off = 1; off < 16; off <<= 1) s += __shfl_xor(s, off, 64);
      s4[r] = s;
    }
    if (li == 0) {
      #pragma unroll
      for (int r = 0; r < 4; ++r)
        *reinterpret_cast<float*>(smem + SSUM_OFF + ((rt * 2 + half) * 16 + quad * 4 + r) * 4) = s4[r];
    }
    __syncthreads();  // (2) ssum ready

    // ---- normalize; write AtF (agg A-operand); compute H -> HF ----
    const int Lt = li + 16 * (rt * 2 + (quad >> 1));
    const int sub = (quad & 1);
    float inv[4];
    #pragma unroll
    for (int r = 0; r < 4; ++r) {
      float other = *reinterpret_cast<float*>(smem + SSUM_OFF + ((rt * 2 + (1 - half)) * 16 + quad * 4 + r) * 4);
      inv[r] = 1.0f / (s4[r] + other);
    }
    for (int j = 0; j < nWa; ++j) {
      int g = half * 6 + j;
      float a0 = accT[j][0] * inv[0], a1 = accT[j][1] * inv[1];
      float a2 = accT[j][2] * inv[2], a3 = accT[j][3] * inv[3];
      massA[j] += a0 + a1 + a2 + a3;
      uint2 pk; pk.x = pack2(a0, a1); pk.y = pack2(a2, a3);
      *reinterpret_cast<uint2*>(smem + AT_OFF + g * 1024 + Lt * 16 + sub * 8) = pk;
    }
    if (half == 1) {
      #pragma unroll
      for (int j = 2; j < 6; ++j) {
        int ce = j - 2;
        int e_col = ce * 16 + li;
        int ks3 = e_col >> 5;
        int Lh = (quad * 4) + (((e_col >> 3) & 3) << 4);
        #pragma unroll
        for (int r = 0; r < 4; ++r) {
          float h = accT[j][r];
          h = h >= 0.f ? h : NEG * h;
          *reinterpret_cast<unsigned short*>(
            smem + HF_OFF + ((rt * 2 + ks3) * 64 + Lh + r) * 16 + (e_col & 7) * 2) = f2bf(h);
        }
      }
    }
    __syncthreads();  // (3) HF + AtF ready

    // ---- GEMM3: S = H @ W2^T + b2 ----
    f32x4 sacc[2];
    sacc[0] = (f32x4){0.f, 0.f, 0.f, 0.f};
    sacc[1] = (f32x4){0.f, 0.f, 0.f, 0.f};
    #pragma unroll
    for (int ks3 = 0; ks3 < 2; ++ks3) {
      bf16x8 ha = ldf(smem, HF_OFF + ((rt * 2 + ks3) * 64 + lane) * 16);
      #pragma unroll
      for (int c = 0; c < 2; ++c) {
        bf16x8 wf = ldf(smem, W2_OFF + (((half * 2 + c) * 2 + ks3) * 64 + lane) * 16);
        sacc[c] = __builtin_amdgcn_mfma_f32_16x16x32_bf16(ha, wf, sacc[c], 0, 0, 0);
      }
    }
    #pragma unroll
    for (int c = 0; c < 2; ++c) {
      int ct3 = half * 2 + c;
      float v0 = sacc[c][0] + b2r[c], v1 = sacc[c][1] + b2r[c];
      float v2 = sacc[c][2] + b2r[c], v3 = sacc[c][3] + b2r[c];
      uint2 pk; pk.x = pack2(v0, v1); pk.y = pack2(v2, v3);
      *reinterpret_cast<uint2*>(smem + SF_OFF + ct3 * 1024 + Lt * 16 + sub * 8) = pk;
    }
    __syncthreads();  // (4) SF ready (and XF_{it+1} writes drained)

    // ---- aggregation: agg[k][d] += A^T S over this iter's 32 rows ----
    bf16x8 sfr[4];
    #pragma unroll
    for (int nt = 0; nt < 4; ++nt) sfr[nt] = ldf(smem, SF_OFF + (nt * 64 + lane) * 16);
    #pragma unroll
    for (int m = 0; m < 2; ++m) {
      bf16x8 af = ldf(smem, AT_OFF + ((w * 2 + m) * 64 + lane) * 16);
      #pragma unroll
      for (int nt = 0; nt < 4; ++nt)
        gacc[m][nt] = __builtin_amdgcn_mfma_f32_16x16x32_bf16(af, sfr[nt], gacc[m][nt], 0, 0, 0);
    }
    // next iter's At/SF/HF writes happen after barriers (1)/(2) of that iter,
    // by which time every wave has finished these reads.
  }

  // ---- flush agg accumulators ----
  float* aggB = agg + (size_t)b * (K_ * DC_);
  #pragma unroll
  for (int m = 0; m < 2; ++m) {
    int kbase = (w * 2 + m) * 16 + quad * 4;
    #pragma unroll
    for (int nt = 0; nt < 4; ++nt) {
      int d = nt * 16 + li;
      #pragma unroll
      for (int r = 0; r < 4; ++r)
        atomicAdd(&aggB[(kbase + r) * DC_ + d], gacc[m][nt][r]);
    }
  }
  // ---- mass: reduce over quads, one atomic per (wave, Wa-tile, li) ----
  for (int j = 0; j < nWa; ++j) {
    float v = massA[j];
    v += __shfl_xor(v, 16, 64);
    v += __shfl_xor(v, 32, 64);
    if (lane < 16) {
      int g = half * 6 + j;
      atomicAdd(&mass[b * K_ + g * 16 + li], v);
    }
  }
}

__global__ __launch_bounds__(1024)
void netvlad_phase2(const float* __restrict__ agg, const float* __restrict__ mass,
                    const float* __restrict__ centroid, float* __restrict__ out)
{
  __shared__ float v[K_ * DC_];
  __shared__ float red[16];
  const int b = blockIdx.x, t = threadIdx.x;
  float ss = 0.f;
  for (int idx = t; idx < K_ * DC_; idx += 1024) {
    int k = idx >> 6;
    float val = agg[(size_t)b * K_ * DC_ + idx] - mass[b * K_ + k] * centroid[idx];
    v[idx] = val;
    ss += val * val;
  }
  #pragma unroll
  for (int off = 32; off > 0; off >>= 1) ss += __shfl_down(ss, off, 64);
  if ((t & 63) == 0) red[t >> 6] = ss;
  __syncthreads();
  if (t == 0) {
    float s = 0.f;
    #pragma unroll
    for (int i = 0; i < 16; ++i) s += red[i];
    red[0] = 1.0f / fmaxf(sqrtf(s), 1e-12f);
  }
  __syncthreads();
  float inv = red[0];
  for (int idx = t; idx < K_ * DC_; idx += 1024)
    out[(size_t)b * K_ * DC_ + idx] = v[idx] * inv;
}

extern "C" void kernel_launch(void* const* d_in, const int* in_sizes, int n_in,
                              void* d_out, int out_size, void* d_ws, size_t ws_size,
                              hipStream_t stream) {
  const float* desc     = (const float*)d_in[0];
  const float* W1       = (const float*)d_in[1];
  const float* b1       = (const float*)d_in[2];
  const float* W2       = (const float*)d_in[3];
  const float* b2       = (const float*)d_in[4];
  const float* Wa       = (const float*)d_in[5];
  const float* ba       = (const float*)d_in[6];
  const float* centroid = (const float*)d_in[7];
  float* out = (float*)d_out;

  float* agg  = (float*)d_ws;                 // B*K*Dc
  float* mass = agg + B_ * K_ * DC_;          // B*K
  size_t zbytes = (size_t)(B_ * K_ * DC_ + B_ * K_) * sizeof(float);
  hipMemsetAsync(d_ws, 0, zbytes, stream);

  hipFuncSetAttribute(reinterpret_cast<const void*>(netvlad_phase1),
                      hipFuncAttributeMaxDynamicSharedMemorySize, LDS_BYTES);

  netvlad_phase1<<<dim3(B_ * 8), dim3(256), LDS_BYTES, stream>>>(
      desc, W1, b1, W2, b2, Wa, ba, agg, mass);
  netvlad_phase2<<<dim3(B_), dim3(1024), 0, stream>>>(agg, mass, centroid, out);
}